// Round 14
// baseline (309.288 us; speedup 1.0000x reference)
//
#include <hip/hip_runtime.h>
#include <math.h>

#define HEADS 4
#define CH 128
#define HC 512
#define GRAPHS 128
#define OUT_DIM 8
#define PCHUNK 4096   // edges per partition block

typedef unsigned short u16;
typedef unsigned int u32;
typedef short short8 __attribute__((ext_vector_type(8)));
typedef float f32x4 __attribute__((ext_vector_type(4)));
typedef float f32x2 __attribute__((ext_vector_type(2)));

__device__ inline u16 f2b(float f) {
  u32 u = __float_as_uint(f);
  u32 r = u + 0x7FFFu + ((u >> 16) & 1u);
  return (u16)(r >> 16);
}
__device__ inline float blo(u32 d) { return __uint_as_float(d << 16); }
__device__ inline float bhi(u32 d) { return __uint_as_float(d & 0xffff0000u); }
__device__ inline f32x2 bunpack(u32 d) {
  f32x2 r; r.x = blo(d); r.y = bhi(d); return r;
}
__device__ inline float lrelu(float v) { return v > 0.f ? v : 0.2f * v; }
__device__ inline int rdl(int v, int l) { return __builtin_amdgcn_readlane(v, l); }
__device__ inline float rdlf(float v, int l) {
  return __int_as_float(__builtin_amdgcn_readlane(__float_as_int(v), l));
}

// ---------------- CSR build: scans ----------------
__global__ __launch_bounds__(256) void k_scanA(const int* __restrict__ counts,
                                               int* __restrict__ bsum, int N) {
  __shared__ int sh[256];
  int b = blockIdx.x, t = threadIdx.x, i = b * 256 + t;
  sh[t] = (i < N) ? counts[i] : 0;
  __syncthreads();
  for (int off = 128; off; off >>= 1) {
    if (t < off) sh[t] += sh[t + off];
    __syncthreads();
  }
  if (t == 0) bsum[b] = sh[0];
}

__global__ __launch_bounds__(1024) void k_scanB(const int* __restrict__ bsum,
                                                int* __restrict__ boff, int nb) {
  __shared__ int sh[1024];
  int t = threadIdx.x;
  sh[t] = (t < nb) ? bsum[t] : 0;
  __syncthreads();
  for (int off = 1; off < 1024; off <<= 1) {
    int v = sh[t];
    int u = (t >= off) ? sh[t - off] : 0;
    __syncthreads();
    sh[t] = v + u;
    __syncthreads();
  }
  if (t < nb) boff[t] = (t == 0) ? 0 : sh[t - 1];
}

__global__ __launch_bounds__(256) void k_scanC(const int* __restrict__ counts,
                                               const int* __restrict__ boff,
                                               int* __restrict__ indptr, int N) {
  __shared__ int sh[256];
  int b = blockIdx.x, t = threadIdx.x, i = b * 256 + t;
  int v = (i < N) ? counts[i] : 0;
  sh[t] = v;
  __syncthreads();
  for (int off = 1; off < 256; off <<= 1) {
    int a = sh[t];
    int u = (t >= off) ? sh[t - off] : 0;
    __syncthreads();
    sh[t] = a + u;
    __syncthreads();
  }
  if (i < N) {
    int excl = boff[b] + sh[t] - v;
    indptr[i] = excl;
    if (i == N - 1) indptr[N] = excl + v;
  }
}

// ---------------- merged weight prep: W1t, W2t, wst ----------------
__global__ __launch_bounds__(256) void k_wprep(const float* __restrict__ W1,
                                               const float* __restrict__ W2,
                                               const float* __restrict__ as1,
                                               const float* __restrict__ ad1,
                                               u16* __restrict__ W1t,
                                               u16* __restrict__ W2t,
                                               u16* __restrict__ wst) {
  int b = blockIdx.x, t = threadIdx.x;
  if (b < 256) {
    int i = b * 256 + t;
    int n = i >> 7, k = i & 127;
    W1t[i] = f2b(W1[(size_t)k * HC + n]);
  } else if (b < 512) {
    int i = (b - 256) * 256 + t;
    int n = i >> 9, k = i & 511;
    W2t[i] = f2b(W2[(size_t)k * CH + n]);
  } else {
    for (int idx = t; idx < 16 * 128; idx += 256) {
      int o = idx >> 7, k = idx & 127;
      float s = 0.f;
      if (o < 8) {
        int h = o & 3;
        const float* av = ((o < 4) ? as1 : ad1) + h * CH;
        const float* wrow = W1 + (size_t)k * HC + h * CH;
        for (int c = 0; c < CH; c++) s += wrow[c] * av[c];
      }
      wst[idx] = f2b(s);
    }
  }
}

// ---------------- merged: edge counting + bucket histogram + x->bf16 ----------------
__global__ __launch_bounds__(256) void k_count_prep(
    const int* __restrict__ ei, int* __restrict__ counts,
    int* __restrict__ blockhist, int E, int N, int PB,
    const float* __restrict__ x, uint2* __restrict__ xb2) {
  int t = threadIdx.x;
  if ((int)blockIdx.x < PB) {
    __shared__ int hist[256];
    hist[t] = 0;
    __syncthreads();
    int total = E + N;
    int base = blockIdx.x * PCHUNK;
    #pragma unroll 4
    for (int u = 0; u < 16; u++) {
      int i = base + u * 256 + t;
      if (i < total) {
        int d = (i < E) ? ei[E + i] : (i - E);
        atomicAdd(&counts[d], 1);
        atomicAdd(&hist[d >> 8], 1);
      }
    }
    __syncthreads();
    blockhist[blockIdx.x * 256 + t] = hist[t];
    return;
  }
  int i = ((int)blockIdx.x - PB) * 256 + t;   // over N*32 float4s
  if (i >= N * 32) return;
  float4 v = ((const float4*)x)[i];
  uint2 o;
  o.x = (u32)f2b(v.x) | ((u32)f2b(v.y) << 16);
  o.y = (u32)f2b(v.z) | ((u32)f2b(v.w) << 16);
  xb2[i] = o;
}

// ---------------- per-bucket column scan ----------------
__global__ __launch_bounds__(256) void k_colscan(const int* __restrict__ blockhist,
                                                 const int* __restrict__ indptr,
                                                 int* __restrict__ gbase, int N, int PB) {
  int b = threadIdx.x;
  int nb0 = b << 8; if (nb0 > N) nb0 = N;
  int run = indptr[nb0];
  #pragma unroll 8
  for (int p = 0; p < PB; p++) {
    int h = blockhist[p * 256 + b];
    gbase[p * 256 + b] = run;
    run += h;
  }
}

// ---------------- place: write (src,dst) pairs bucket-grouped ----------------
__global__ __launch_bounds__(256) void k_place(const int* __restrict__ ei,
                                               const int* __restrict__ gbase,
                                               uint2* __restrict__ bpairs,
                                               int E, int N) {
  __shared__ int hist[256];
  int t = threadIdx.x;
  hist[t] = 0;
  __syncthreads();
  int total = E + N;
  int base = blockIdx.x * PCHUNK;
  int lrank[16];
  #pragma unroll 4
  for (int u = 0; u < 16; u++) {
    int i = base + u * 256 + t;
    lrank[u] = -1;
    if (i < total) {
      int d = (i < E) ? ei[E + i] : (i - E);
      lrank[u] = atomicAdd(&hist[d >> 8], 1);
    }
  }
  const int* gb = gbase + blockIdx.x * 256;
  #pragma unroll 4
  for (int u = 0; u < 16; u++) {
    if (lrank[u] >= 0) {
      int i = base + u * 256 + t;
      int s, d;
      if (i < E) { s = ei[i]; d = ei[E + i]; } else { s = i - E; d = i - E; }
      bpairs[gb[d >> 8] + lrank[u]] = make_uint2((u32)s, (u32)d);
    }
  }
}

// ---------------- per-bucket final scatter ----------------
__global__ __launch_bounds__(256) void k_scatter2(const uint2* __restrict__ bpairs,
                                                  const int* __restrict__ indptr,
                                                  int* __restrict__ srcs, int N) {
  __shared__ int curs[256];
  int b = blockIdx.x, t = threadIdx.x;
  int nbeg = b << 8;
  int nend = nbeg + 256; if (nend > N) nend = N;
  int ebeg = indptr[nbeg], eend = indptr[nend];
  curs[t] = 0;
  __syncthreads();
  for (int i = ebeg + t; i < eend; i += 256) {
    uint2 p = bpairs[i];
    int d = (int)p.y;
    int r = atomicAdd(&curs[d - nbeg], 1);
    srcs[indptr[d] + r] = (int)p.x;
  }
}

// ---------------- conv1 scores via MFMA ----------------
__global__ __launch_bounds__(256) void k_score(
    const u16* __restrict__ xb, const u16* __restrict__ wst,
    float* __restrict__ sa1, float* __restrict__ da1, int N) {
  int lane = threadIdx.x & 63, wid = threadIdx.x >> 6;
  int base = (blockIdx.x * 4 + wid) * 64;
  if (base >= N) return;
  int lr = lane & 15, lk = lane >> 4;
  short8 bfrag[4];
  #pragma unroll
  for (int ks = 0; ks < 4; ks++)
    bfrag[ks] = *(const short8*)(wst + lr * 128 + ks * 32 + lk * 8);
  #pragma unroll
  for (int rt = 0; rt < 4; rt++) {
    int r0 = base + rt * 16;
    if (r0 >= N) break;
    f32x4 acc = {};
    int row = r0 + lr; if (row >= N) row = N - 1;
    #pragma unroll
    for (int ks = 0; ks < 4; ks++) {
      short8 afrag = *(const short8*)(xb + (size_t)row * 128 + ks * 32 + lk * 8);
      acc = __builtin_amdgcn_mfma_f32_16x16x32_bf16(afrag, bfrag[ks], acc, 0, 0, 0);
    }
    int col = lr;
    #pragma unroll
    for (int r = 0; r < 4; r++) {
      int n = r0 + lk * 4 + r;
      if (n < N) {
        if (col < 4) sa1[n * 4 + col] = acc[r];
        else if (col < 8) da1[n * 4 + (col - 4)] = acc[r];
      }
    }
  }
}

// ---------------- conv1 aggregation over x (bf16), 4 heads ----------------
// Two nodes per wave; readlane src; LDS-broadcast weights; 16 loads in flight.
__global__ __launch_bounds__(256) void k_aggx(
    const u32* __restrict__ xb, const int* __restrict__ indptr,
    const int* __restrict__ srcs, const float4* __restrict__ as1,
    const float4* __restrict__ ad1, u32* __restrict__ aggx, int N) {
  __shared__ __align__(16) float s_w0[4][64][4];
  __shared__ __align__(16) float s_w1[4][64][4];
  int t = threadIdx.x;
  int lane = t & 63, wid = t >> 6;
  int n0 = blockIdx.x * 8 + wid * 2;
  if (n0 >= N) return;
  int n1 = n0 + 1;
  bool has1 = n1 < N;
  int beg0 = indptr[n0], end0 = indptr[n0 + 1];
  int beg1 = end0, end1 = has1 ? indptr[n1 + 1] : end0;
  int deg0 = end0 - beg0, deg1 = end1 - beg1;
  float4 ad0 = ad1[n0];
  float4 adv1 = has1 ? ad1[n1] : make_float4(0.f, 0.f, 0.f, 0.f);

  if (deg0 <= 64 && deg1 <= 64) {
    int s0 = 0, s1 = 0;
    float w0[4] = {}, w1[4] = {};
    if (lane < deg0) {
      s0 = srcs[beg0 + lane];
      float4 a = as1[s0];
      w0[0] = __expf(lrelu(a.x + ad0.x)); w0[1] = __expf(lrelu(a.y + ad0.y));
      w0[2] = __expf(lrelu(a.z + ad0.z)); w0[3] = __expf(lrelu(a.w + ad0.w));
    }
    if (lane < deg1) {
      s1 = srcs[beg1 + lane];
      float4 a = as1[s1];
      w1[0] = __expf(lrelu(a.x + adv1.x)); w1[1] = __expf(lrelu(a.y + adv1.y));
      w1[2] = __expf(lrelu(a.z + adv1.z)); w1[3] = __expf(lrelu(a.w + adv1.w));
    }
    *(float4*)&s_w0[wid][lane][0] = make_float4(w0[0], w0[1], w0[2], w0[3]);
    *(float4*)&s_w1[wid][lane][0] = make_float4(w1[0], w1[1], w1[2], w1[3]);
    f32x2 c0[4] = {}, c1[4] = {};
    int dboth = (deg0 < deg1 ? deg0 : deg1) & ~7;
    int j = 0;
    for (; j < dboth; j += 8) {
      u32 d[8], e[8];
      #pragma unroll
      for (int u = 0; u < 8; u++) d[u] = xb[(size_t)rdl(s0, j + u) * 64 + lane];
      #pragma unroll
      for (int u = 0; u < 8; u++) e[u] = xb[(size_t)rdl(s1, j + u) * 64 + lane];
      #pragma unroll
      for (int u = 0; u < 8; u++) {
        f32x2 xv = bunpack(d[u]);
        f32x2 yv = bunpack(e[u]);
        float4 wv0 = *(const float4*)&s_w0[wid][j + u][0];
        float4 wv1 = *(const float4*)&s_w1[wid][j + u][0];
        c0[0] += xv * wv0.x; c0[1] += xv * wv0.y; c0[2] += xv * wv0.z; c0[3] += xv * wv0.w;
        c1[0] += yv * wv1.x; c1[1] += yv * wv1.y; c1[2] += yv * wv1.z; c1[3] += yv * wv1.w;
      }
    }
    int pad0 = (deg0 + 3) & ~3;
    for (int ja = j; ja < pad0; ja += 4) {
      u32 d[4];
      #pragma unroll
      for (int u = 0; u < 4; u++) d[u] = xb[(size_t)rdl(s0, ja + u) * 64 + lane];
      #pragma unroll
      for (int u = 0; u < 4; u++) {
        f32x2 xv = bunpack(d[u]);
        float4 wv0 = *(const float4*)&s_w0[wid][ja + u][0];
        c0[0] += xv * wv0.x; c0[1] += xv * wv0.y; c0[2] += xv * wv0.z; c0[3] += xv * wv0.w;
      }
    }
    int pad1 = (deg1 + 3) & ~3;
    for (int jb = j; jb < pad1; jb += 4) {
      u32 e[4];
      #pragma unroll
      for (int u = 0; u < 4; u++) e[u] = xb[(size_t)rdl(s1, jb + u) * 64 + lane];
      #pragma unroll
      for (int u = 0; u < 4; u++) {
        f32x2 yv = bunpack(e[u]);
        float4 wv1 = *(const float4*)&s_w1[wid][jb + u][0];
        c1[0] += yv * wv1.x; c1[1] += yv * wv1.y; c1[2] += yv * wv1.z; c1[3] += yv * wv1.w;
      }
    }
    float e0[4], e1[4];
    #pragma unroll
    for (int h = 0; h < 4; h++) {
      float v0 = w0[h], v1 = w1[h];
      #pragma unroll
      for (int off = 32; off; off >>= 1) {
        v0 += __shfl_xor(v0, off);
        v1 += __shfl_xor(v1, off);
      }
      e0[h] = v0; e1[h] = v1;
    }
    {
      u32* orow = aggx + (size_t)n0 * 256;
      #pragma unroll
      for (int h = 0; h < 4; h++) {
        float iv = 1.f / (e0[h] + 1e-16f);
        orow[h * 64 + lane] = (u32)f2b(c0[h].x * iv) | ((u32)f2b(c0[h].y * iv) << 16);
      }
    }
    if (has1) {
      u32* orow = aggx + (size_t)n1 * 256;
      #pragma unroll
      for (int h = 0; h < 4; h++) {
        float iv = 1.f / (e1[h] + 1e-16f);
        orow[h * 64 + lane] = (u32)f2b(c1[h].x * iv) | ((u32)f2b(c1[h].y * iv) << 16);
      }
    }
    return;
  }
  // slow path (deg > 64)
  for (int pass = 0; pass < 2; pass++) {
    if (pass == 1 && !has1) break;
    int n = pass ? n1 : n0;
    int beg = pass ? beg1 : beg0;
    int end = pass ? end1 : end0;
    float4 ad = pass ? adv1 : ad0;
    float e0[4] = {};
    f32x2 c0[4] = {};
    for (int base = beg; base < end; base += 64) {
      int cnt = min(64, end - base);
      int sreg = 0;
      float w0[4] = {};
      if (lane < cnt) {
        sreg = srcs[base + lane];
        float4 a = as1[sreg];
        w0[0] = __expf(lrelu(a.x + ad.x)); w0[1] = __expf(lrelu(a.y + ad.y));
        w0[2] = __expf(lrelu(a.z + ad.z)); w0[3] = __expf(lrelu(a.w + ad.w));
      }
      int cpad = (cnt + 1) & ~1;
      for (int j = 0; j < cpad; j += 2) {
        u32 dA = xb[(size_t)rdl(sreg, j) * 64 + lane];
        u32 dB = xb[(size_t)rdl(sreg, j + 1) * 64 + lane];
        f32x2 xA = bunpack(dA), xB = bunpack(dB);
        #pragma unroll
        for (int h = 0; h < 4; h++) {
          float a = rdlf(w0[h], j), b = rdlf(w0[h], j + 1);
          e0[h] += a + b;
          c0[h] += xA * a;
          c0[h] += xB * b;
        }
      }
    }
    u32* orow = aggx + (size_t)n * 256;
    #pragma unroll
    for (int h = 0; h < 4; h++) {
      float iv = 1.f / (e0[h] + 1e-16f);
      orow[h * 64 + lane] = (u32)f2b(c0[h].x * iv) | ((u32)f2b(c0[h].y * iv) << 16);
    }
  }
}

// ---------------- per-head GEMM ----------------
__global__ __launch_bounds__(256) void k_gemm_head(
    const u16* __restrict__ A, const u16* __restrict__ Bt,
    const float* __restrict__ bias, u16* __restrict__ C, int M) {
  __shared__ u16 As[128 * 64];
  __shared__ u16 Bs[128 * 64];
  int t = threadIdx.x;
  int lane = t & 63, wid = t >> 6;
  int wr = wid >> 1, wc = wid & 1;
  int r0 = blockIdx.x * 128;
  int hh = blockIdx.y;
  const u16* Ah = A + hh * 128;
  const u16* Bh = Bt + (size_t)hh * 128 * 128;
  int lr = lane & 15, lk = lane >> 4;
  f32x4 acc[4][4] = {};
  for (int kt = 0; kt < 128; kt += 64) {
    #pragma unroll
    for (int it = 0; it < 4; it++) {
      int q = wid * 4096 + it * 1024 + lane * 16;
      int row = q >> 7;
      int soff = ((q >> 4) & 7) ^ (row & 7);
      {
        int gr = r0 + row; if (gr >= M) gr = M - 1;
        const u16* gp = Ah + (size_t)gr * 512 + kt + soff * 8;
        __builtin_amdgcn_global_load_lds(
            (const __attribute__((address_space(1))) void*)gp,
            (__attribute__((address_space(3))) void*)((char*)As + wid * 4096 + it * 1024),
            16, 0, 0);
      }
      {
        const u16* gp = Bh + (size_t)row * 128 + kt + soff * 8;
        __builtin_amdgcn_global_load_lds(
            (const __attribute__((address_space(1))) void*)gp,
            (__attribute__((address_space(3))) void*)((char*)Bs + wid * 4096 + it * 1024),
            16, 0, 0);
      }
    }
    __syncthreads();
    const char* Ab = (const char*)As;
    const char* Bb = (const char*)Bs;
    #pragma unroll
    for (int kk = 0; kk < 2; kk++) {
      short8 a[4], b[4];
      #pragma unroll
      for (int m = 0; m < 4; m++) {
        int row = wr * 64 + m * 16 + lr;
        int off = (row << 7) + kk * 64 + lk * 16;
        off ^= (row & 7) << 4;
        a[m] = *(const short8*)(Ab + off);
      }
      #pragma unroll
      for (int nn = 0; nn < 4; nn++) {
        int row = wc * 64 + nn * 16 + lr;
        int off = (row << 7) + kk * 64 + lk * 16;
        off ^= (row & 7) << 4;
        b[nn] = *(const short8*)(Bb + off);
      }
      #pragma unroll
      for (int m = 0; m < 4; m++)
        #pragma unroll
        for (int nn = 0; nn < 4; nn++)
          acc[m][nn] = __builtin_amdgcn_mfma_f32_16x16x32_bf16(a[m], b[nn], acc[m][nn], 0, 0, 0);
    }
    __syncthreads();
  }
  #pragma unroll
  for (int m = 0; m < 4; m++)
    #pragma unroll
    for (int nn = 0; nn < 4; nn++)
      #pragma unroll
      for (int r = 0; r < 4; r++) {
        int row = r0 + wr * 64 + m * 16 + lk * 4 + r;
        if (row < M) {
          int gcol = hh * 128 + wc * 64 + nn * 16 + lr;
          C[(size_t)row * 512 + gcol] = f2b(acc[m][nn][r] + bias[gcol]);
        }
      }
}

// ---------------- LN+ReLU over 512 channels ----------------
__global__ __launch_bounds__(256) void k_ln512(const u16* __restrict__ raw,
                                               const float* __restrict__ gam,
                                               const float* __restrict__ bet,
                                               u16* __restrict__ out, int N) {
  int n = blockIdx.x * 4 + (threadIdx.x >> 6);
  int lane = threadIdx.x & 63;
  if (n >= N) return;
  const uint4* r = (const uint4*)(raw + (size_t)n * 512);
  uint4 q = r[lane];
  float v[8];
  v[0] = blo(q.x); v[1] = bhi(q.x); v[2] = blo(q.y); v[3] = bhi(q.y);
  v[4] = blo(q.z); v[5] = bhi(q.z); v[6] = blo(q.w); v[7] = bhi(q.w);
  float s1 = 0.f, s2 = 0.f;
  #pragma unroll
  for (int j = 0; j < 8; j++) { s1 += v[j]; s2 += v[j] * v[j]; }
  #pragma unroll
  for (int off = 32; off; off >>= 1) {
    s1 += __shfl_xor(s1, off);
    s2 += __shfl_xor(s2, off);
  }
  float mean = s1 * (1.f / 512.f);
  float var = s2 * (1.f / 512.f) - mean * mean;
  float rs = rsqrtf(var + 1e-5f);
  u32 o[4];
  #pragma unroll
  for (int j = 0; j < 4; j++) {
    int ch = lane * 8 + 2 * j;
    float y0 = fmaxf((v[2 * j] - mean) * rs * gam[ch] + bet[ch], 0.f);
    float y1 = fmaxf((v[2 * j + 1] - mean) * rs * gam[ch + 1] + bet[ch + 1], 0.f);
    o[j] = (u32)f2b(y0) | ((u32)f2b(y1) << 16);
  }
  ((uint4*)(out + (size_t)n * 512))[lane] = make_uint4(o[0], o[1], o[2], o[3]);
}

// ---------------- conv2 GEMM + fused attention scores ----------------
// C[M][128] = A[M][512] @ Bt[128][512]^T; epilogue computes sa2/da2 row dots.
__global__ __launch_bounds__(256) void k_gemm2_att(
    const u16* __restrict__ A, const u16* __restrict__ Bt,
    const float* __restrict__ att_s, const float* __restrict__ att_d,
    u16* __restrict__ C, float* __restrict__ sa2, float* __restrict__ da2, int M) {
  __shared__ u16 As[128 * 64];
  __shared__ u16 Bs[128 * 64];
  __shared__ float sred[2][128][2];
  int t = threadIdx.x;
  int lane = t & 63, wid = t >> 6;
  int wr = wid >> 1, wc = wid & 1;
  int r0 = blockIdx.x * 128;
  int lr = lane & 15, lk = lane >> 4;
  f32x4 acc[4][4] = {};
  for (int kt = 0; kt < 512; kt += 64) {
    #pragma unroll
    for (int it = 0; it < 4; it++) {
      int q = wid * 4096 + it * 1024 + lane * 16;
      int row = q >> 7;
      int soff = ((q >> 4) & 7) ^ (row & 7);
      {
        int gr = r0 + row; if (gr >= M) gr = M - 1;
        const u16* gp = A + (size_t)gr * 512 + kt + soff * 8;
        __builtin_amdgcn_global_load_lds(
            (const __attribute__((address_space(1))) void*)gp,
            (__attribute__((address_space(3))) void*)((char*)As + wid * 4096 + it * 1024),
            16, 0, 0);
      }
      {
        const u16* gp = Bt + (size_t)row * 512 + kt + soff * 8;
        __builtin_amdgcn_global_load_lds(
            (const __attribute__((address_space(1))) void*)gp,
            (__attribute__((address_space(3))) void*)((char*)Bs + wid * 4096 + it * 1024),
            16, 0, 0);
      }
    }
    __syncthreads();
    const char* Ab = (const char*)As;
    const char* Bb = (const char*)Bs;
    #pragma unroll
    for (int kk = 0; kk < 2; kk++) {
      short8 a[4], b[4];
      #pragma unroll
      for (int m = 0; m < 4; m++) {
        int row = wr * 64 + m * 16 + lr;
        int off = (row << 7) + kk * 64 + lk * 16;
        off ^= (row & 7) << 4;
        a[m] = *(const short8*)(Ab + off);
      }
      #pragma unroll
      for (int nn = 0; nn < 4; nn++) {
        int row = wc * 64 + nn * 16 + lr;
        int off = (row << 7) + kk * 64 + lk * 16;
        off ^= (row & 7) << 4;
        b[nn] = *(const short8*)(Bb + off);
      }
      #pragma unroll
      for (int m = 0; m < 4; m++)
        #pragma unroll
        for (int nn = 0; nn < 4; nn++)
          acc[m][nn] = __builtin_amdgcn_mfma_f32_16x16x32_bf16(a[m], b[nn], acc[m][nn], 0, 0, 0);
    }
    __syncthreads();
  }
  // C write
  #pragma unroll
  for (int m = 0; m < 4; m++)
    #pragma unroll
    for (int nn = 0; nn < 4; nn++)
      #pragma unroll
      for (int r = 0; r < 4; r++) {
        int row = r0 + wr * 64 + m * 16 + lk * 4 + r;
        if (row < M) {
          int col = wc * 64 + nn * 16 + lr;
          C[(size_t)row * 128 + col] = f2b(acc[m][nn][r]);
        }
      }
  // fused attention score epilogue
  float asv[4], adv[4];
  #pragma unroll
  for (int nn = 0; nn < 4; nn++) {
    int col = wc * 64 + nn * 16 + lr;
    asv[nn] = att_s[col];
    adv[nn] = att_d[col];
  }
  #pragma unroll
  for (int m = 0; m < 4; m++)
    #pragma unroll
    for (int r = 0; r < 4; r++) {
      float ps = 0.f, pd = 0.f;
      #pragma unroll
      for (int nn = 0; nn < 4; nn++) {
        ps += acc[m][nn][r] * asv[nn];
        pd += acc[m][nn][r] * adv[nn];
      }
      #pragma unroll
      for (int off = 1; off < 16; off <<= 1) {
        ps += __shfl_xor(ps, off);
        pd += __shfl_xor(pd, off);
      }
      if (lr == 0) {
        int rl = wr * 64 + m * 16 + lk * 4 + r;
        sred[wc][rl][0] = ps;
        sred[wc][rl][1] = pd;
      }
    }
  __syncthreads();
  if (t < 128) {
    int row = r0 + t;
    if (row < M) {
      sa2[row] = sred[0][t][0] + sred[1][t][0];
      da2[row] = sred[0][t][1] + sred[1][t][1];
    }
  }
}

// ---------------- conv2 aggregation + bias + LN + ReLU -> h2 ----------------
__global__ __launch_bounds__(256) void k_agg2f(
    const u32* __restrict__ raw2, const int* __restrict__ indptr,
    const int* __restrict__ srcs, const float* __restrict__ as2,
    const float* __restrict__ ad2, const float* __restrict__ bias,
    const float* __restrict__ gam, const float* __restrict__ bet,
    float* __restrict__ h2, int N) {
  int t = threadIdx.x;
  int lane = t & 63, wid = t >> 6;
  int n0 = blockIdx.x * 8 + wid * 2;
  if (n0 >= N) return;
  int n1 = n0 + 1;
  bool has1 = n1 < N;
  int beg0 = indptr[n0], end0 = indptr[n0 + 1];
  int beg1 = end0, end1 = has1 ? indptr[n1 + 1] : end0;
  int deg0 = end0 - beg0, deg1 = end1 - beg1;
  float adv0 = ad2[n0];
  float adv1 = has1 ? ad2[n1] : 0.f;
  float ds0 = 0.f, ds1 = 0.f;
  f32x2 acc0 = {0.f, 0.f}, acc1 = {0.f, 0.f};

  if (deg0 <= 64 && deg1 <= 64) {
    int s0 = 0, s1r = 0;
    float w0 = 0.f, w1 = 0.f;
    if (lane < deg0) { s0 = srcs[beg0 + lane]; w0 = __expf(lrelu(as2[s0] + adv0)); }
    if (lane < deg1) { s1r = srcs[beg1 + lane]; w1 = __expf(lrelu(as2[s1r] + adv1)); }
    int dboth = (deg0 < deg1 ? deg0 : deg1) & ~7;
    int j = 0;
    for (; j < dboth; j += 8) {
      u32 d[8], e[8];
      #pragma unroll
      for (int u = 0; u < 8; u++) d[u] = raw2[(size_t)rdl(s0, j + u) * 64 + lane];
      #pragma unroll
      for (int u = 0; u < 8; u++) e[u] = raw2[(size_t)rdl(s1r, j + u) * 64 + lane];
      #pragma unroll
      for (int u = 0; u < 8; u++) {
        acc0 += bunpack(d[u]) * rdlf(w0, j + u);
        acc1 += bunpack(e[u]) * rdlf(w1, j + u);
      }
    }
    int pad0 = (deg0 + 3) & ~3;
    for (int ja = j; ja < pad0; ja += 4) {
      u32 d[4];
      #pragma unroll
      for (int u = 0; u < 4; u++) d[u] = raw2[(size_t)rdl(s0, ja + u) * 64 + lane];
      #pragma unroll
      for (int u = 0; u < 4; u++) acc0 += bunpack(d[u]) * rdlf(w0, ja + u);
    }
    int pad1 = (deg1 + 3) & ~3;
    for (int jb = j; jb < pad1; jb += 4) {
      u32 e[4];
      #pragma unroll
      for (int u = 0; u < 4; u++) e[u] = raw2[(size_t)rdl(s1r, jb + u) * 64 + lane];
      #pragma unroll
      for (int u = 0; u < 4; u++) acc1 += bunpack(e[u]) * rdlf(w1, jb + u);
    }
    float v0 = w0, v1 = w1;
    #pragma unroll
    for (int off = 32; off; off >>= 1) {
      v0 += __shfl_xor(v0, off);
      v1 += __shfl_xor(v1, off);
    }
    ds0 = v0; ds1 = v1;
  } else {
    for (int pass = 0; pass < 2; pass++) {
      if (pass == 1 && !has1) break;
      int beg = pass ? beg1 : beg0;
      int end = pass ? end1 : end0;
      float adv = pass ? adv1 : adv0;
      for (int base = beg; base < end; base += 64) {
        int cnt = min(64, end - base);
        int sreg = 0;
        float w = 0.f;
        if (lane < cnt) { sreg = srcs[base + lane]; w = __expf(lrelu(as2[sreg] + adv)); }
        int cpad = (cnt + 3) & ~3;
        for (int j = 0; j < cpad; j += 4) {
          u32 dA = raw2[(size_t)rdl(sreg, j) * 64 + lane];
          u32 dB = raw2[(size_t)rdl(sreg, j + 1) * 64 + lane];
          u32 dC = raw2[(size_t)rdl(sreg, j + 2) * 64 + lane];
          u32 dD = raw2[(size_t)rdl(sreg, j + 3) * 64 + lane];
          float wA = rdlf(w, j), wB = rdlf(w, j + 1);
          float wC = rdlf(w, j + 2), wD = rdlf(w, j + 3);
          f32x2 s = bunpack(dA) * wA;
          s += bunpack(dB) * wB;
          s += bunpack(dC) * wC;
          s += bunpack(dD) * wD;
          float sw = (wA + wB) + (wC + wD);
          if (pass) { ds1 += sw; acc1 += s; }
          else      { ds0 += sw; acc0 += s; }
        }
      }
    }
  }

  float inv0 = 1.f / (ds0 + 1e-16f);
  float v00 = acc0.x * inv0 + bias[2 * lane];
  float v01 = acc0.y * inv0 + bias[2 * lane + 1];
  float s1a = v00 + v01, s2a = v00 * v00 + v01 * v01;
  float inv1 = 1.f / (ds1 + 1e-16f);
  float v10 = acc1.x * inv1 + bias[2 * lane];
  float v11 = acc1.y * inv1 + bias[2 * lane + 1];
  float s1b = v10 + v11, s2b = v10 * v10 + v11 * v11;
  #pragma unroll
  for (int off = 32; off; off >>= 1) {
    s1a += __shfl_xor(s1a, off);
    s2a += __shfl_xor(s2a, off);
    s1b += __shfl_xor(s1b, off);
    s2b += __shfl_xor(s2b, off);
  }
  {
    float mean = s1a * (1.f / 128.f);
    float var = s2a * (1.f / 128.f) - mean * mean;
    float rs = rsqrtf(var + 1e-5f);
    float y0 = fmaxf((v00 - mean) * rs * gam[2 * lane] + bet[2 * lane], 0.f);
    float y1 = fmaxf((v01 - mean) * rs * gam[2 * lane + 1] + bet[2 * lane + 1], 0.f);
    ((float2*)(h2 + (size_t)n0 * 128))[lane] = make_float2(y0, y1);
  }
  if (has1) {
    float mean = s1b * (1.f / 128.f);
    float var = s2b * (1.f / 128.f) - mean * mean;
    float rs = rsqrtf(var + 1e-5f);
    float y0 = fmaxf((v10 - mean) * rs * gam[2 * lane] + bet[2 * lane], 0.f);
    float y1 = fmaxf((v11 - mean) * rs * gam[2 * lane + 1] + bet[2 * lane + 1], 0.f);
    ((float2*)(h2 + (size_t)n1 * 128))[lane] = make_float2(y0, y1);
  }
}

// ---------------- MLP head with segment-sum pooling ----------------
__global__ __launch_bounds__(256) void k_head(const float* __restrict__ h2,
    const int* __restrict__ batch, int N,
    const float* __restrict__ rW1, const float* __restrict__ rb1,
    const float* __restrict__ rg, const float* __restrict__ rbe,
    const float* __restrict__ rW2, const float* __restrict__ rb2,
    float* __restrict__ outp) {
  int g = blockIdx.x, t = threadIdx.x;
  int ch = t & 127, half = t >> 7;
  __shared__ float part[2][128];
  __shared__ float pl[128];
  __shared__ float yv[32];
  __shared__ float rv[32];
  __shared__ float mv[2];
  __shared__ int sseg[2];
  if (t == 0) {
    int lo = 0, hi = N;
    while (lo < hi) { int mid = (lo + hi) >> 1; if (batch[mid] < g) lo = mid + 1; else hi = mid; }
    int lo2 = lo, hi2 = N;
    while (lo2 < hi2) { int mid = (lo2 + hi2) >> 1; if (batch[mid] < g + 1) lo2 = mid + 1; else hi2 = mid; }
    sseg[0] = lo; sseg[1] = lo2;
  }
  __syncthreads();
  int lo = sseg[0], hi = sseg[1];
  float s = 0.f;
  int n = lo + half;
  for (; n + 8 <= hi; n += 8) {
    s += h2[(size_t)n * 128 + ch] + h2[(size_t)(n + 2) * 128 + ch]
       + h2[(size_t)(n + 4) * 128 + ch] + h2[(size_t)(n + 6) * 128 + ch];
  }
  for (; n < hi; n += 2) s += h2[(size_t)n * 128 + ch];
  part[half][ch] = s;
  __syncthreads();
  float cnt = fmaxf((float)(hi - lo), 1.f);
  if (t < 128) pl[t] = (part[0][t] + part[1][t]) / cnt;
  __syncthreads();
  if (t < 32) {
    float sum = rb1[t];
    for (int c = 0; c < 128; c++) sum += pl[c] * rW1[c * 32 + t];
    yv[t] = sum;
  }
  __syncthreads();
  if (t == 0) {
    float sm = 0.f, sq = 0.f;
    for (int j = 0; j < 32; j++) { sm += yv[j]; sq += yv[j] * yv[j]; }
    float mean = sm / 32.f;
    float var = sq / 32.f - mean * mean;
    mv[0] = mean; mv[1] = rsqrtf(var + 1e-5f);
  }
  __syncthreads();
  if (t < 32) {
    float y = (yv[t] - mv[0]) * mv[1] * rg[t] + rbe[t];
    rv[t] = fmaxf(y, 0.f);
  }
  __syncthreads();
  if (t < OUT_DIM) {
    float sum = rb2[t];
    for (int j = 0; j < 32; j++) sum += rv[j] * rW2[j * 8 + t];
    outp[g * 8 + t] = sum;
  }
}

extern "C" void kernel_launch(void* const* d_in, const int* in_sizes, int n_in,
                              void* d_out, int out_size, void* d_ws, size_t ws_size,
                              hipStream_t stream) {
  const float* x    = (const float*)d_in[0];
  const int*   ei   = (const int*)d_in[1];
  const int*   batch= (const int*)d_in[3];
  const float* W1   = (const float*)d_in[4];
  const float* as1w = (const float*)d_in[5];
  const float* ad1w = (const float*)d_in[6];
  const float* b1   = (const float*)d_in[7];
  const float* g1   = (const float*)d_in[8];
  const float* be1  = (const float*)d_in[9];
  const float* W2   = (const float*)d_in[10];
  const float* as2w = (const float*)d_in[11];
  const float* ad2w = (const float*)d_in[12];
  const float* b2   = (const float*)d_in[13];
  const float* g2   = (const float*)d_in[14];
  const float* be2  = (const float*)d_in[15];
  const float* rW1  = (const float*)d_in[16];
  const float* rb1  = (const float*)d_in[17];
  const float* rg   = (const float*)d_in[18];
  const float* rbe  = (const float*)d_in[19];
  const float* rW2  = (const float*)d_in[20];
  const float* rb2  = (const float*)d_in[21];

  int N = in_sizes[0] / 128;
  int E = in_sizes[1] / 2;
  int ET = E + N;
  int nb = (N + 255) / 256;
  int PB = (ET + PCHUNK - 1) / PCHUNK;
  int nbk = (N + 255) >> 8;

  char* p = (char*)d_ws;
  u16* x_b   = (u16*)p; p += (size_t)N * 128 * 2;
  u16* aggx  = (u16*)p; p += (size_t)N * 512 * 2;
  u16* raw1  = (u16*)p; p += (size_t)N * 512 * 2;
  u16* h1_b  = (u16*)p; p += (size_t)N * 512 * 2;
  u16* raw2b = (u16*)p; p += (size_t)N * 128 * 2;
  float* h2  = (float*)p; p += (size_t)N * 128 * 4;
  u16* W1t   = (u16*)p; p += 512 * 128 * 2;
  u16* W2t   = (u16*)p; p += 128 * 512 * 2;
  u16* wst   = (u16*)p; p += 16 * 128 * 2;
  float* sa1 = (float*)p; p += (size_t)N * 4 * 4;
  float* da1 = (float*)p; p += (size_t)N * 4 * 4;
  float* sa2 = (float*)p; p += (size_t)N * 4;
  float* da2 = (float*)p; p += (size_t)N * 4;
  int* counts = (int*)p; p += (size_t)N * 4;
  int* indptr = (int*)p; p += (size_t)(N + 1) * 4;
  int* bsum   = (int*)p; p += (size_t)nb * 4;
  int* boff   = (int*)p; p += (size_t)nb * 4;
  int* blockhist = (int*)p; p += (size_t)PB * 256 * 4;
  int* gbase  = (int*)p; p += (size_t)PB * 256 * 4;
  int* srcs   = (int*)p; p += (size_t)ET * 4;
  uint2* bpairs = (uint2*)p; p += (size_t)ET * 8;

  hipMemsetAsync(counts, 0, (size_t)N * sizeof(int), stream);

  // weight prep
  k_wprep<<<513, 256, 0, stream>>>(W1, W2, as1w, ad1w, W1t, W2t, wst);

  // edge counting + bucket histogram + x->bf16
  int cb = (N * 32 + 255) / 256;
  k_count_prep<<<PB + cb, 256, 0, stream>>>(ei, counts, blockhist, E, N, PB,
                                            x, (uint2*)x_b);

  // conv1 scores via MFMA
  k_score<<<(N + 255) / 256, 256, 0, stream>>>(x_b, wst, sa1, da1, N);

  // CSR indptr
  k_scanA<<<nb, 256, 0, stream>>>(counts, bsum, N);
  k_scanB<<<1, 1024, 0, stream>>>(bsum, boff, nb);
  k_scanC<<<nb, 256, 0, stream>>>(counts, boff, indptr, N);

  // contention-free bucket partition then per-bucket scatter
  k_colscan<<<1, 256, 0, stream>>>(blockhist, indptr, gbase, N, PB);
  k_place<<<PB, 256, 0, stream>>>(ei, gbase, bpairs, E, N);
  k_scatter2<<<nbk, 256, 0, stream>>>(bpairs, indptr, srcs, N);

  // conv1
  k_aggx<<<(N + 7) / 8, 256, 0, stream>>>((const u32*)x_b, indptr, srcs,
                                          (const float4*)sa1, (const float4*)da1,
                                          (u32*)aggx, N);
  dim3 gridh((N + 127) / 128, 4);
  k_gemm_head<<<gridh, 256, 0, stream>>>(aggx, W1t, b1, raw1, N);
  k_ln512<<<(N + 3) / 4, 256, 0, stream>>>(raw1, g1, be1, h1_b, N);

  // conv2: GEMM with fused attention-score epilogue
  k_gemm2_att<<<(N + 127) / 128, 256, 0, stream>>>(h1_b, W2t, as2w, ad2w,
                                                   raw2b, sa2, da2, N);
  k_agg2f<<<(N + 7) / 8, 256, 0, stream>>>((const u32*)raw2b, indptr, srcs, sa2, da2,
                                           b2, g2, be2, h2, N);

  // head
  k_head<<<GRAPHS, 256, 0, stream>>>(h2, batch, N, rW1, rb1, rg, rbe, rW2, rb2,
                                     (float*)d_out);
}

// Round 15
// 300.898 us; speedup vs baseline: 1.0279x; 1.0279x over previous
//
#include <hip/hip_runtime.h>
#include <math.h>

#define HEADS 4
#define CH 128
#define HC 512
#define GRAPHS 128
#define OUT_DIM 8
#define PCHUNK 4096   // edges per partition block

typedef unsigned short u16;
typedef unsigned int u32;
typedef short short8 __attribute__((ext_vector_type(8)));
typedef float f32x4 __attribute__((ext_vector_type(4)));
typedef float f32x2 __attribute__((ext_vector_type(2)));

__device__ inline u16 f2b(float f) {
  u32 u = __float_as_uint(f);
  u32 r = u + 0x7FFFu + ((u >> 16) & 1u);
  return (u16)(r >> 16);
}
__device__ inline float blo(u32 d) { return __uint_as_float(d << 16); }
__device__ inline float bhi(u32 d) { return __uint_as_float(d & 0xffff0000u); }
__device__ inline f32x2 bunpack(u32 d) {
  f32x2 r; r.x = blo(d); r.y = bhi(d); return r;
}
__device__ inline float lrelu(float v) { return v > 0.f ? v : 0.2f * v; }
__device__ inline int rdl(int v, int l) { return __builtin_amdgcn_readlane(v, l); }
__device__ inline float rdlf(float v, int l) {
  return __int_as_float(__builtin_amdgcn_readlane(__float_as_int(v), l));
}

// ---------------- CSR build: scans ----------------
__global__ __launch_bounds__(256) void k_scanA(const int* __restrict__ counts,
                                               int* __restrict__ bsum, int N) {
  __shared__ int sh[256];
  int b = blockIdx.x, t = threadIdx.x, i = b * 256 + t;
  sh[t] = (i < N) ? counts[i] : 0;
  __syncthreads();
  for (int off = 128; off; off >>= 1) {
    if (t < off) sh[t] += sh[t + off];
    __syncthreads();
  }
  if (t == 0) bsum[b] = sh[0];
}

__global__ __launch_bounds__(1024) void k_scanB(const int* __restrict__ bsum,
                                                int* __restrict__ boff, int nb) {
  __shared__ int sh[1024];
  int t = threadIdx.x;
  sh[t] = (t < nb) ? bsum[t] : 0;
  __syncthreads();
  for (int off = 1; off < 1024; off <<= 1) {
    int v = sh[t];
    int u = (t >= off) ? sh[t - off] : 0;
    __syncthreads();
    sh[t] = v + u;
    __syncthreads();
  }
  if (t < nb) boff[t] = (t == 0) ? 0 : sh[t - 1];
}

__global__ __launch_bounds__(256) void k_scanC(const int* __restrict__ counts,
                                               const int* __restrict__ boff,
                                               int* __restrict__ indptr, int N) {
  __shared__ int sh[256];
  int b = blockIdx.x, t = threadIdx.x, i = b * 256 + t;
  int v = (i < N) ? counts[i] : 0;
  sh[t] = v;
  __syncthreads();
  for (int off = 1; off < 256; off <<= 1) {
    int a = sh[t];
    int u = (t >= off) ? sh[t - off] : 0;
    __syncthreads();
    sh[t] = a + u;
    __syncthreads();
  }
  if (i < N) {
    int excl = boff[b] + sh[t] - v;
    indptr[i] = excl;
    if (i == N - 1) indptr[N] = excl + v;
  }
}

// ---------------- merged weight prep: W1t, W2t, wst ----------------
__global__ __launch_bounds__(256) void k_wprep(const float* __restrict__ W1,
                                               const float* __restrict__ W2,
                                               const float* __restrict__ as1,
                                               const float* __restrict__ ad1,
                                               u16* __restrict__ W1t,
                                               u16* __restrict__ W2t,
                                               u16* __restrict__ wst) {
  int b = blockIdx.x, t = threadIdx.x;
  if (b < 256) {
    int i = b * 256 + t;
    int n = i >> 7, k = i & 127;
    W1t[i] = f2b(W1[(size_t)k * HC + n]);
  } else if (b < 512) {
    int i = (b - 256) * 256 + t;
    int n = i >> 9, k = i & 511;
    W2t[i] = f2b(W2[(size_t)k * CH + n]);
  } else {
    for (int idx = t; idx < 16 * 128; idx += 256) {
      int o = idx >> 7, k = idx & 127;
      float s = 0.f;
      if (o < 8) {
        int h = o & 3;
        const float* av = ((o < 4) ? as1 : ad1) + h * CH;
        const float* wrow = W1 + (size_t)k * HC + h * CH;
        for (int c = 0; c < CH; c++) s += wrow[c] * av[c];
      }
      wst[idx] = f2b(s);
    }
  }
}

// ---------------- merged: edge counting + bucket histogram + x->bf16 ----------------
__global__ __launch_bounds__(256) void k_count_prep(
    const int* __restrict__ ei, int* __restrict__ counts,
    int* __restrict__ blockhist, int E, int N, int PB,
    const float* __restrict__ x, uint2* __restrict__ xb2) {
  int t = threadIdx.x;
  if ((int)blockIdx.x < PB) {
    __shared__ int hist[256];
    hist[t] = 0;
    __syncthreads();
    int total = E + N;
    int base = blockIdx.x * PCHUNK;
    #pragma unroll 4
    for (int u = 0; u < 16; u++) {
      int i = base + u * 256 + t;
      if (i < total) {
        int d = (i < E) ? ei[E + i] : (i - E);
        atomicAdd(&counts[d], 1);
        atomicAdd(&hist[d >> 8], 1);
      }
    }
    __syncthreads();
    blockhist[blockIdx.x * 256 + t] = hist[t];
    return;
  }
  int i = ((int)blockIdx.x - PB) * 256 + t;   // over N*32 float4s
  if (i >= N * 32) return;
  float4 v = ((const float4*)x)[i];
  uint2 o;
  o.x = (u32)f2b(v.x) | ((u32)f2b(v.y) << 16);
  o.y = (u32)f2b(v.z) | ((u32)f2b(v.w) << 16);
  xb2[i] = o;
}

// ---------------- per-bucket column scan ----------------
__global__ __launch_bounds__(256) void k_colscan(const int* __restrict__ blockhist,
                                                 const int* __restrict__ indptr,
                                                 int* __restrict__ gbase, int N, int PB) {
  int b = threadIdx.x;
  int nb0 = b << 8; if (nb0 > N) nb0 = N;
  int run = indptr[nb0];
  #pragma unroll 8
  for (int p = 0; p < PB; p++) {
    int h = blockhist[p * 256 + b];
    gbase[p * 256 + b] = run;
    run += h;
  }
}

// ---------------- place: write (src,dst) pairs bucket-grouped ----------------
__global__ __launch_bounds__(256) void k_place(const int* __restrict__ ei,
                                               const int* __restrict__ gbase,
                                               uint2* __restrict__ bpairs,
                                               int E, int N) {
  __shared__ int hist[256];
  int t = threadIdx.x;
  hist[t] = 0;
  __syncthreads();
  int total = E + N;
  int base = blockIdx.x * PCHUNK;
  int lrank[16];
  #pragma unroll 4
  for (int u = 0; u < 16; u++) {
    int i = base + u * 256 + t;
    lrank[u] = -1;
    if (i < total) {
      int d = (i < E) ? ei[E + i] : (i - E);
      lrank[u] = atomicAdd(&hist[d >> 8], 1);
    }
  }
  const int* gb = gbase + blockIdx.x * 256;
  #pragma unroll 4
  for (int u = 0; u < 16; u++) {
    if (lrank[u] >= 0) {
      int i = base + u * 256 + t;
      int s, d;
      if (i < E) { s = ei[i]; d = ei[E + i]; } else { s = i - E; d = i - E; }
      bpairs[gb[d >> 8] + lrank[u]] = make_uint2((u32)s, (u32)d);
    }
  }
}

// ---------------- per-bucket final scatter ----------------
__global__ __launch_bounds__(256) void k_scatter2(const uint2* __restrict__ bpairs,
                                                  const int* __restrict__ indptr,
                                                  int* __restrict__ srcs, int N) {
  __shared__ int curs[256];
  int b = blockIdx.x, t = threadIdx.x;
  int nbeg = b << 8;
  int nend = nbeg + 256; if (nend > N) nend = N;
  int ebeg = indptr[nbeg], eend = indptr[nend];
  curs[t] = 0;
  __syncthreads();
  for (int i = ebeg + t; i < eend; i += 256) {
    uint2 p = bpairs[i];
    int d = (int)p.y;
    int r = atomicAdd(&curs[d - nbeg], 1);
    srcs[indptr[d] + r] = (int)p.x;
  }
}

// ---------------- conv1 scores via MFMA ----------------
__global__ __launch_bounds__(256) void k_score(
    const u16* __restrict__ xb, const u16* __restrict__ wst,
    float* __restrict__ sa1, float* __restrict__ da1, int N) {
  int lane = threadIdx.x & 63, wid = threadIdx.x >> 6;
  int base = (blockIdx.x * 4 + wid) * 64;
  if (base >= N) return;
  int lr = lane & 15, lk = lane >> 4;
  short8 bfrag[4];
  #pragma unroll
  for (int ks = 0; ks < 4; ks++)
    bfrag[ks] = *(const short8*)(wst + lr * 128 + ks * 32 + lk * 8);
  #pragma unroll
  for (int rt = 0; rt < 4; rt++) {
    int r0 = base + rt * 16;
    if (r0 >= N) break;
    f32x4 acc = {};
    int row = r0 + lr; if (row >= N) row = N - 1;
    #pragma unroll
    for (int ks = 0; ks < 4; ks++) {
      short8 afrag = *(const short8*)(xb + (size_t)row * 128 + ks * 32 + lk * 8);
      acc = __builtin_amdgcn_mfma_f32_16x16x32_bf16(afrag, bfrag[ks], acc, 0, 0, 0);
    }
    int col = lr;
    #pragma unroll
    for (int r = 0; r < 4; r++) {
      int n = r0 + lk * 4 + r;
      if (n < N) {
        if (col < 4) sa1[n * 4 + col] = acc[r];
        else if (col < 8) da1[n * 4 + (col - 4)] = acc[r];
      }
    }
  }
}

// ---------------- conv1 aggregation over x (bf16), 4 heads ----------------
// Two nodes per wave; readlane src; LDS-broadcast weights; 8 loads in flight (R13 config).
__global__ __launch_bounds__(256) void k_aggx(
    const u32* __restrict__ xb, const int* __restrict__ indptr,
    const int* __restrict__ srcs, const float4* __restrict__ as1,
    const float4* __restrict__ ad1, u32* __restrict__ aggx, int N) {
  __shared__ __align__(16) float s_w0[4][64][4];
  __shared__ __align__(16) float s_w1[4][64][4];
  int t = threadIdx.x;
  int lane = t & 63, wid = t >> 6;
  int n0 = blockIdx.x * 8 + wid * 2;
  if (n0 >= N) return;
  int n1 = n0 + 1;
  bool has1 = n1 < N;
  int beg0 = indptr[n0], end0 = indptr[n0 + 1];
  int beg1 = end0, end1 = has1 ? indptr[n1 + 1] : end0;
  int deg0 = end0 - beg0, deg1 = end1 - beg1;
  float4 ad0 = ad1[n0];
  float4 adv1 = has1 ? ad1[n1] : make_float4(0.f, 0.f, 0.f, 0.f);

  if (deg0 <= 64 && deg1 <= 64) {
    int s0 = 0, s1 = 0;
    float w0[4] = {}, w1[4] = {};
    if (lane < deg0) {
      s0 = srcs[beg0 + lane];
      float4 a = as1[s0];
      w0[0] = __expf(lrelu(a.x + ad0.x)); w0[1] = __expf(lrelu(a.y + ad0.y));
      w0[2] = __expf(lrelu(a.z + ad0.z)); w0[3] = __expf(lrelu(a.w + ad0.w));
    }
    if (lane < deg1) {
      s1 = srcs[beg1 + lane];
      float4 a = as1[s1];
      w1[0] = __expf(lrelu(a.x + adv1.x)); w1[1] = __expf(lrelu(a.y + adv1.y));
      w1[2] = __expf(lrelu(a.z + adv1.z)); w1[3] = __expf(lrelu(a.w + adv1.w));
    }
    *(float4*)&s_w0[wid][lane][0] = make_float4(w0[0], w0[1], w0[2], w0[3]);
    *(float4*)&s_w1[wid][lane][0] = make_float4(w1[0], w1[1], w1[2], w1[3]);
    f32x2 c0[4] = {}, c1[4] = {};
    int dboth = (deg0 < deg1 ? deg0 : deg1) & ~3;
    int j = 0;
    for (; j < dboth; j += 4) {
      u32 d[4], e[4];
      #pragma unroll
      for (int u = 0; u < 4; u++) d[u] = xb[(size_t)rdl(s0, j + u) * 64 + lane];
      #pragma unroll
      for (int u = 0; u < 4; u++) e[u] = xb[(size_t)rdl(s1, j + u) * 64 + lane];
      #pragma unroll
      for (int u = 0; u < 4; u++) {
        f32x2 xv = bunpack(d[u]);
        f32x2 yv = bunpack(e[u]);
        float4 wv0 = *(const float4*)&s_w0[wid][j + u][0];
        float4 wv1 = *(const float4*)&s_w1[wid][j + u][0];
        c0[0] += xv * wv0.x; c0[1] += xv * wv0.y; c0[2] += xv * wv0.z; c0[3] += xv * wv0.w;
        c1[0] += yv * wv1.x; c1[1] += yv * wv1.y; c1[2] += yv * wv1.z; c1[3] += yv * wv1.w;
      }
    }
    int pad0 = (deg0 + 3) & ~3;
    for (int ja = j; ja < pad0; ja += 4) {
      u32 d[4];
      #pragma unroll
      for (int u = 0; u < 4; u++) d[u] = xb[(size_t)rdl(s0, ja + u) * 64 + lane];
      #pragma unroll
      for (int u = 0; u < 4; u++) {
        f32x2 xv = bunpack(d[u]);
        float4 wv0 = *(const float4*)&s_w0[wid][ja + u][0];
        c0[0] += xv * wv0.x; c0[1] += xv * wv0.y; c0[2] += xv * wv0.z; c0[3] += xv * wv0.w;
      }
    }
    int pad1 = (deg1 + 3) & ~3;
    for (int jb = j; jb < pad1; jb += 4) {
      u32 e[4];
      #pragma unroll
      for (int u = 0; u < 4; u++) e[u] = xb[(size_t)rdl(s1, jb + u) * 64 + lane];
      #pragma unroll
      for (int u = 0; u < 4; u++) {
        f32x2 yv = bunpack(e[u]);
        float4 wv1 = *(const float4*)&s_w1[wid][jb + u][0];
        c1[0] += yv * wv1.x; c1[1] += yv * wv1.y; c1[2] += yv * wv1.z; c1[3] += yv * wv1.w;
      }
    }
    float e0[4], e1[4];
    #pragma unroll
    for (int h = 0; h < 4; h++) {
      float v0 = w0[h], v1 = w1[h];
      #pragma unroll
      for (int off = 32; off; off >>= 1) {
        v0 += __shfl_xor(v0, off);
        v1 += __shfl_xor(v1, off);
      }
      e0[h] = v0; e1[h] = v1;
    }
    {
      u32* orow = aggx + (size_t)n0 * 256;
      #pragma unroll
      for (int h = 0; h < 4; h++) {
        float iv = 1.f / (e0[h] + 1e-16f);
        orow[h * 64 + lane] = (u32)f2b(c0[h].x * iv) | ((u32)f2b(c0[h].y * iv) << 16);
      }
    }
    if (has1) {
      u32* orow = aggx + (size_t)n1 * 256;
      #pragma unroll
      for (int h = 0; h < 4; h++) {
        float iv = 1.f / (e1[h] + 1e-16f);
        orow[h * 64 + lane] = (u32)f2b(c1[h].x * iv) | ((u32)f2b(c1[h].y * iv) << 16);
      }
    }
    return;
  }
  // slow path (deg > 64)
  for (int pass = 0; pass < 2; pass++) {
    if (pass == 1 && !has1) break;
    int n = pass ? n1 : n0;
    int beg = pass ? beg1 : beg0;
    int end = pass ? end1 : end0;
    float4 ad = pass ? adv1 : ad0;
    float e0[4] = {};
    f32x2 c0[4] = {};
    for (int base = beg; base < end; base += 64) {
      int cnt = min(64, end - base);
      int sreg = 0;
      float w0[4] = {};
      if (lane < cnt) {
        sreg = srcs[base + lane];
        float4 a = as1[sreg];
        w0[0] = __expf(lrelu(a.x + ad.x)); w0[1] = __expf(lrelu(a.y + ad.y));
        w0[2] = __expf(lrelu(a.z + ad.z)); w0[3] = __expf(lrelu(a.w + ad.w));
      }
      int cpad = (cnt + 1) & ~1;
      for (int j = 0; j < cpad; j += 2) {
        u32 dA = xb[(size_t)rdl(sreg, j) * 64 + lane];
        u32 dB = xb[(size_t)rdl(sreg, j + 1) * 64 + lane];
        f32x2 xA = bunpack(dA), xB = bunpack(dB);
        #pragma unroll
        for (int h = 0; h < 4; h++) {
          float a = rdlf(w0[h], j), b = rdlf(w0[h], j + 1);
          e0[h] += a + b;
          c0[h] += xA * a;
          c0[h] += xB * b;
        }
      }
    }
    u32* orow = aggx + (size_t)n * 256;
    #pragma unroll
    for (int h = 0; h < 4; h++) {
      float iv = 1.f / (e0[h] + 1e-16f);
      orow[h * 64 + lane] = (u32)f2b(c0[h].x * iv) | ((u32)f2b(c0[h].y * iv) << 16);
    }
  }
}

// ---------------- per-head GEMM ----------------
__global__ __launch_bounds__(256) void k_gemm_head(
    const u16* __restrict__ A, const u16* __restrict__ Bt,
    const float* __restrict__ bias, u16* __restrict__ C, int M) {
  __shared__ u16 As[128 * 64];
  __shared__ u16 Bs[128 * 64];
  int t = threadIdx.x;
  int lane = t & 63, wid = t >> 6;
  int wr = wid >> 1, wc = wid & 1;
  int r0 = blockIdx.x * 128;
  int hh = blockIdx.y;
  const u16* Ah = A + hh * 128;
  const u16* Bh = Bt + (size_t)hh * 128 * 128;
  int lr = lane & 15, lk = lane >> 4;
  f32x4 acc[4][4] = {};
  for (int kt = 0; kt < 128; kt += 64) {
    #pragma unroll
    for (int it = 0; it < 4; it++) {
      int q = wid * 4096 + it * 1024 + lane * 16;
      int row = q >> 7;
      int soff = ((q >> 4) & 7) ^ (row & 7);
      {
        int gr = r0 + row; if (gr >= M) gr = M - 1;
        const u16* gp = Ah + (size_t)gr * 512 + kt + soff * 8;
        __builtin_amdgcn_global_load_lds(
            (const __attribute__((address_space(1))) void*)gp,
            (__attribute__((address_space(3))) void*)((char*)As + wid * 4096 + it * 1024),
            16, 0, 0);
      }
      {
        const u16* gp = Bh + (size_t)row * 128 + kt + soff * 8;
        __builtin_amdgcn_global_load_lds(
            (const __attribute__((address_space(1))) void*)gp,
            (__attribute__((address_space(3))) void*)((char*)Bs + wid * 4096 + it * 1024),
            16, 0, 0);
      }
    }
    __syncthreads();
    const char* Ab = (const char*)As;
    const char* Bb = (const char*)Bs;
    #pragma unroll
    for (int kk = 0; kk < 2; kk++) {
      short8 a[4], b[4];
      #pragma unroll
      for (int m = 0; m < 4; m++) {
        int row = wr * 64 + m * 16 + lr;
        int off = (row << 7) + kk * 64 + lk * 16;
        off ^= (row & 7) << 4;
        a[m] = *(const short8*)(Ab + off);
      }
      #pragma unroll
      for (int nn = 0; nn < 4; nn++) {
        int row = wc * 64 + nn * 16 + lr;
        int off = (row << 7) + kk * 64 + lk * 16;
        off ^= (row & 7) << 4;
        b[nn] = *(const short8*)(Bb + off);
      }
      #pragma unroll
      for (int m = 0; m < 4; m++)
        #pragma unroll
        for (int nn = 0; nn < 4; nn++)
          acc[m][nn] = __builtin_amdgcn_mfma_f32_16x16x32_bf16(a[m], b[nn], acc[m][nn], 0, 0, 0);
    }
    __syncthreads();
  }
  #pragma unroll
  for (int m = 0; m < 4; m++)
    #pragma unroll
    for (int nn = 0; nn < 4; nn++)
      #pragma unroll
      for (int r = 0; r < 4; r++) {
        int row = r0 + wr * 64 + m * 16 + lk * 4 + r;
        if (row < M) {
          int gcol = hh * 128 + wc * 64 + nn * 16 + lr;
          C[(size_t)row * 512 + gcol] = f2b(acc[m][nn][r] + bias[gcol]);
        }
      }
}

// ---------------- LN+ReLU over 512 channels ----------------
__global__ __launch_bounds__(256) void k_ln512(const u16* __restrict__ raw,
                                               const float* __restrict__ gam,
                                               const float* __restrict__ bet,
                                               u16* __restrict__ out, int N) {
  int n = blockIdx.x * 4 + (threadIdx.x >> 6);
  int lane = threadIdx.x & 63;
  if (n >= N) return;
  const uint4* r = (const uint4*)(raw + (size_t)n * 512);
  uint4 q = r[lane];
  float v[8];
  v[0] = blo(q.x); v[1] = bhi(q.x); v[2] = blo(q.y); v[3] = bhi(q.y);
  v[4] = blo(q.z); v[5] = bhi(q.z); v[6] = blo(q.w); v[7] = bhi(q.w);
  float s1 = 0.f, s2 = 0.f;
  #pragma unroll
  for (int j = 0; j < 8; j++) { s1 += v[j]; s2 += v[j] * v[j]; }
  #pragma unroll
  for (int off = 32; off; off >>= 1) {
    s1 += __shfl_xor(s1, off);
    s2 += __shfl_xor(s2, off);
  }
  float mean = s1 * (1.f / 512.f);
  float var = s2 * (1.f / 512.f) - mean * mean;
  float rs = rsqrtf(var + 1e-5f);
  u32 o[4];
  #pragma unroll
  for (int j = 0; j < 4; j++) {
    int ch = lane * 8 + 2 * j;
    float y0 = fmaxf((v[2 * j] - mean) * rs * gam[ch] + bet[ch], 0.f);
    float y1 = fmaxf((v[2 * j + 1] - mean) * rs * gam[ch + 1] + bet[ch + 1], 0.f);
    o[j] = (u32)f2b(y0) | ((u32)f2b(y1) << 16);
  }
  ((uint4*)(out + (size_t)n * 512))[lane] = make_uint4(o[0], o[1], o[2], o[3]);
}

// ---------------- conv2 GEMM + fused attention scores ----------------
__global__ __launch_bounds__(256) void k_gemm2_att(
    const u16* __restrict__ A, const u16* __restrict__ Bt,
    const float* __restrict__ att_s, const float* __restrict__ att_d,
    u16* __restrict__ C, float* __restrict__ sa2, float* __restrict__ da2, int M) {
  __shared__ u16 As[128 * 64];
  __shared__ u16 Bs[128 * 64];
  __shared__ float sred[2][128][2];
  int t = threadIdx.x;
  int lane = t & 63, wid = t >> 6;
  int wr = wid >> 1, wc = wid & 1;
  int r0 = blockIdx.x * 128;
  int lr = lane & 15, lk = lane >> 4;
  f32x4 acc[4][4] = {};
  for (int kt = 0; kt < 512; kt += 64) {
    #pragma unroll
    for (int it = 0; it < 4; it++) {
      int q = wid * 4096 + it * 1024 + lane * 16;
      int row = q >> 7;
      int soff = ((q >> 4) & 7) ^ (row & 7);
      {
        int gr = r0 + row; if (gr >= M) gr = M - 1;
        const u16* gp = A + (size_t)gr * 512 + kt + soff * 8;
        __builtin_amdgcn_global_load_lds(
            (const __attribute__((address_space(1))) void*)gp,
            (__attribute__((address_space(3))) void*)((char*)As + wid * 4096 + it * 1024),
            16, 0, 0);
      }
      {
        const u16* gp = Bt + (size_t)row * 512 + kt + soff * 8;
        __builtin_amdgcn_global_load_lds(
            (const __attribute__((address_space(1))) void*)gp,
            (__attribute__((address_space(3))) void*)((char*)Bs + wid * 4096 + it * 1024),
            16, 0, 0);
      }
    }
    __syncthreads();
    const char* Ab = (const char*)As;
    const char* Bb = (const char*)Bs;
    #pragma unroll
    for (int kk = 0; kk < 2; kk++) {
      short8 a[4], b[4];
      #pragma unroll
      for (int m = 0; m < 4; m++) {
        int row = wr * 64 + m * 16 + lr;
        int off = (row << 7) + kk * 64 + lk * 16;
        off ^= (row & 7) << 4;
        a[m] = *(const short8*)(Ab + off);
      }
      #pragma unroll
      for (int nn = 0; nn < 4; nn++) {
        int row = wc * 64 + nn * 16 + lr;
        int off = (row << 7) + kk * 64 + lk * 16;
        off ^= (row & 7) << 4;
        b[nn] = *(const short8*)(Bb + off);
      }
      #pragma unroll
      for (int m = 0; m < 4; m++)
        #pragma unroll
        for (int nn = 0; nn < 4; nn++)
          acc[m][nn] = __builtin_amdgcn_mfma_f32_16x16x32_bf16(a[m], b[nn], acc[m][nn], 0, 0, 0);
    }
    __syncthreads();
  }
  #pragma unroll
  for (int m = 0; m < 4; m++)
    #pragma unroll
    for (int nn = 0; nn < 4; nn++)
      #pragma unroll
      for (int r = 0; r < 4; r++) {
        int row = r0 + wr * 64 + m * 16 + lk * 4 + r;
        if (row < M) {
          int col = wc * 64 + nn * 16 + lr;
          C[(size_t)row * 128 + col] = f2b(acc[m][nn][r]);
        }
      }
  float asv[4], adv[4];
  #pragma unroll
  for (int nn = 0; nn < 4; nn++) {
    int col = wc * 64 + nn * 16 + lr;
    asv[nn] = att_s[col];
    adv[nn] = att_d[col];
  }
  #pragma unroll
  for (int m = 0; m < 4; m++)
    #pragma unroll
    for (int r = 0; r < 4; r++) {
      float ps = 0.f, pd = 0.f;
      #pragma unroll
      for (int nn = 0; nn < 4; nn++) {
        ps += acc[m][nn][r] * asv[nn];
        pd += acc[m][nn][r] * adv[nn];
      }
      #pragma unroll
      for (int off = 1; off < 16; off <<= 1) {
        ps += __shfl_xor(ps, off);
        pd += __shfl_xor(pd, off);
      }
      if (lr == 0) {
        int rl = wr * 64 + m * 16 + lk * 4 + r;
        sred[wc][rl][0] = ps;
        sred[wc][rl][1] = pd;
      }
    }
  __syncthreads();
  if (t < 128) {
    int row = r0 + t;
    if (row < M) {
      sa2[row] = sred[0][t][0] + sred[1][t][0];
      da2[row] = sred[0][t][1] + sred[1][t][1];
    }
  }
}

// ---------------- conv2 aggregation + bias + LN + ReLU -> h2 ----------------
__global__ __launch_bounds__(256) void k_agg2f(
    const u32* __restrict__ raw2, const int* __restrict__ indptr,
    const int* __restrict__ srcs, const float* __restrict__ as2,
    const float* __restrict__ ad2, const float* __restrict__ bias,
    const float* __restrict__ gam, const float* __restrict__ bet,
    float* __restrict__ h2, int N) {
  int t = threadIdx.x;
  int lane = t & 63, wid = t >> 6;
  int n0 = blockIdx.x * 8 + wid * 2;
  if (n0 >= N) return;
  int n1 = n0 + 1;
  bool has1 = n1 < N;
  int beg0 = indptr[n0], end0 = indptr[n0 + 1];
  int beg1 = end0, end1 = has1 ? indptr[n1 + 1] : end0;
  int deg0 = end0 - beg0, deg1 = end1 - beg1;
  float adv0 = ad2[n0];
  float adv1 = has1 ? ad2[n1] : 0.f;
  float ds0 = 0.f, ds1 = 0.f;
  f32x2 acc0 = {0.f, 0.f}, acc1 = {0.f, 0.f};

  if (deg0 <= 64 && deg1 <= 64) {
    int s0 = 0, s1r = 0;
    float w0 = 0.f, w1 = 0.f;
    if (lane < deg0) { s0 = srcs[beg0 + lane]; w0 = __expf(lrelu(as2[s0] + adv0)); }
    if (lane < deg1) { s1r = srcs[beg1 + lane]; w1 = __expf(lrelu(as2[s1r] + adv1)); }
    int dboth = (deg0 < deg1 ? deg0 : deg1) & ~7;
    int j = 0;
    for (; j < dboth; j += 8) {
      u32 d[8], e[8];
      #pragma unroll
      for (int u = 0; u < 8; u++) d[u] = raw2[(size_t)rdl(s0, j + u) * 64 + lane];
      #pragma unroll
      for (int u = 0; u < 8; u++) e[u] = raw2[(size_t)rdl(s1r, j + u) * 64 + lane];
      #pragma unroll
      for (int u = 0; u < 8; u++) {
        acc0 += bunpack(d[u]) * rdlf(w0, j + u);
        acc1 += bunpack(e[u]) * rdlf(w1, j + u);
      }
    }
    int pad0 = (deg0 + 3) & ~3;
    for (int ja = j; ja < pad0; ja += 4) {
      u32 d[4];
      #pragma unroll
      for (int u = 0; u < 4; u++) d[u] = raw2[(size_t)rdl(s0, ja + u) * 64 + lane];
      #pragma unroll
      for (int u = 0; u < 4; u++) acc0 += bunpack(d[u]) * rdlf(w0, ja + u);
    }
    int pad1 = (deg1 + 3) & ~3;
    for (int jb = j; jb < pad1; jb += 4) {
      u32 e[4];
      #pragma unroll
      for (int u = 0; u < 4; u++) e[u] = raw2[(size_t)rdl(s1r, jb + u) * 64 + lane];
      #pragma unroll
      for (int u = 0; u < 4; u++) acc1 += bunpack(e[u]) * rdlf(w1, jb + u);
    }
    float v0 = w0, v1 = w1;
    #pragma unroll
    for (int off = 32; off; off >>= 1) {
      v0 += __shfl_xor(v0, off);
      v1 += __shfl_xor(v1, off);
    }
    ds0 = v0; ds1 = v1;
  } else {
    for (int pass = 0; pass < 2; pass++) {
      if (pass == 1 && !has1) break;
      int beg = pass ? beg1 : beg0;
      int end = pass ? end1 : end0;
      float adv = pass ? adv1 : adv0;
      for (int base = beg; base < end; base += 64) {
        int cnt = min(64, end - base);
        int sreg = 0;
        float w = 0.f;
        if (lane < cnt) { sreg = srcs[base + lane]; w = __expf(lrelu(as2[sreg] + adv)); }
        int cpad = (cnt + 3) & ~3;
        for (int j = 0; j < cpad; j += 4) {
          u32 dA = raw2[(size_t)rdl(sreg, j) * 64 + lane];
          u32 dB = raw2[(size_t)rdl(sreg, j + 1) * 64 + lane];
          u32 dC = raw2[(size_t)rdl(sreg, j + 2) * 64 + lane];
          u32 dD = raw2[(size_t)rdl(sreg, j + 3) * 64 + lane];
          float wA = rdlf(w, j), wB = rdlf(w, j + 1);
          float wC = rdlf(w, j + 2), wD = rdlf(w, j + 3);
          f32x2 s = bunpack(dA) * wA;
          s += bunpack(dB) * wB;
          s += bunpack(dC) * wC;
          s += bunpack(dD) * wD;
          float sw = (wA + wB) + (wC + wD);
          if (pass) { ds1 += sw; acc1 += s; }
          else      { ds0 += sw; acc0 += s; }
        }
      }
    }
  }

  float inv0 = 1.f / (ds0 + 1e-16f);
  float v00 = acc0.x * inv0 + bias[2 * lane];
  float v01 = acc0.y * inv0 + bias[2 * lane + 1];
  float s1a = v00 + v01, s2a = v00 * v00 + v01 * v01;
  float inv1 = 1.f / (ds1 + 1e-16f);
  float v10 = acc1.x * inv1 + bias[2 * lane];
  float v11 = acc1.y * inv1 + bias[2 * lane + 1];
  float s1b = v10 + v11, s2b = v10 * v10 + v11 * v11;
  #pragma unroll
  for (int off = 32; off; off >>= 1) {
    s1a += __shfl_xor(s1a, off);
    s2a += __shfl_xor(s2a, off);
    s1b += __shfl_xor(s1b, off);
    s2b += __shfl_xor(s2b, off);
  }
  {
    float mean = s1a * (1.f / 128.f);
    float var = s2a * (1.f / 128.f) - mean * mean;
    float rs = rsqrtf(var + 1e-5f);
    float y0 = fmaxf((v00 - mean) * rs * gam[2 * lane] + bet[2 * lane], 0.f);
    float y1 = fmaxf((v01 - mean) * rs * gam[2 * lane + 1] + bet[2 * lane + 1], 0.f);
    ((float2*)(h2 + (size_t)n0 * 128))[lane] = make_float2(y0, y1);
  }
  if (has1) {
    float mean = s1b * (1.f / 128.f);
    float var = s2b * (1.f / 128.f) - mean * mean;
    float rs = rsqrtf(var + 1e-5f);
    float y0 = fmaxf((v10 - mean) * rs * gam[2 * lane] + bet[2 * lane], 0.f);
    float y1 = fmaxf((v11 - mean) * rs * gam[2 * lane + 1] + bet[2 * lane + 1], 0.f);
    ((float2*)(h2 + (size_t)n1 * 128))[lane] = make_float2(y0, y1);
  }
}

// ---------------- MLP head with segment-sum pooling ----------------
__global__ __launch_bounds__(256) void k_head(const float* __restrict__ h2,
    const int* __restrict__ batch, int N,
    const float* __restrict__ rW1, const float* __restrict__ rb1,
    const float* __restrict__ rg, const float* __restrict__ rbe,
    const float* __restrict__ rW2, const float* __restrict__ rb2,
    float* __restrict__ outp) {
  int g = blockIdx.x, t = threadIdx.x;
  int ch = t & 127, half = t >> 7;
  __shared__ float part[2][128];
  __shared__ float pl[128];
  __shared__ float yv[32];
  __shared__ float rv[32];
  __shared__ float mv[2];
  __shared__ int sseg[2];
  if (t == 0) {
    int lo = 0, hi = N;
    while (lo < hi) { int mid = (lo + hi) >> 1; if (batch[mid] < g) lo = mid + 1; else hi = mid; }
    int lo2 = lo, hi2 = N;
    while (lo2 < hi2) { int mid = (lo2 + hi2) >> 1; if (batch[mid] < g + 1) lo2 = mid + 1; else hi2 = mid; }
    sseg[0] = lo; sseg[1] = lo2;
  }
  __syncthreads();
  int lo = sseg[0], hi = sseg[1];
  float s = 0.f;
  int n = lo + half;
  for (; n + 8 <= hi; n += 8) {
    s += h2[(size_t)n * 128 + ch] + h2[(size_t)(n + 2) * 128 + ch]
       + h2[(size_t)(n + 4) * 128 + ch] + h2[(size_t)(n + 6) * 128 + ch];
  }
  for (; n < hi; n += 2) s += h2[(size_t)n * 128 + ch];
  part[half][ch] = s;
  __syncthreads();
  float cnt = fmaxf((float)(hi - lo), 1.f);
  if (t < 128) pl[t] = (part[0][t] + part[1][t]) / cnt;
  __syncthreads();
  if (t < 32) {
    float sum = rb1[t];
    for (int c = 0; c < 128; c++) sum += pl[c] * rW1[c * 32 + t];
    yv[t] = sum;
  }
  __syncthreads();
  if (t == 0) {
    float sm = 0.f, sq = 0.f;
    for (int j = 0; j < 32; j++) { sm += yv[j]; sq += yv[j] * yv[j]; }
    float mean = sm / 32.f;
    float var = sq / 32.f - mean * mean;
    mv[0] = mean; mv[1] = rsqrtf(var + 1e-5f);
  }
  __syncthreads();
  if (t < 32) {
    float y = (yv[t] - mv[0]) * mv[1] * rg[t] + rbe[t];
    rv[t] = fmaxf(y, 0.f);
  }
  __syncthreads();
  if (t < OUT_DIM) {
    float sum = rb2[t];
    for (int j = 0; j < 32; j++) sum += rv[j] * rW2[j * 8 + t];
    outp[g * 8 + t] = sum;
  }
}

extern "C" void kernel_launch(void* const* d_in, const int* in_sizes, int n_in,
                              void* d_out, int out_size, void* d_ws, size_t ws_size,
                              hipStream_t stream) {
  const float* x    = (const float*)d_in[0];
  const int*   ei   = (const int*)d_in[1];
  const int*   batch= (const int*)d_in[3];
  const float* W1   = (const float*)d_in[4];
  const float* as1w = (const float*)d_in[5];
  const float* ad1w = (const float*)d_in[6];
  const float* b1   = (const float*)d_in[7];
  const float* g1   = (const float*)d_in[8];
  const float* be1  = (const float*)d_in[9];
  const float* W2   = (const float*)d_in[10];
  const float* as2w = (const float*)d_in[11];
  const float* ad2w = (const float*)d_in[12];
  const float* b2   = (const float*)d_in[13];
  const float* g2   = (const float*)d_in[14];
  const float* be2  = (const float*)d_in[15];
  const float* rW1  = (const float*)d_in[16];
  const float* rb1  = (const float*)d_in[17];
  const float* rg   = (const float*)d_in[18];
  const float* rbe  = (const float*)d_in[19];
  const float* rW2  = (const float*)d_in[20];
  const float* rb2  = (const float*)d_in[21];

  int N = in_sizes[0] / 128;
  int E = in_sizes[1] / 2;
  int ET = E + N;
  int nb = (N + 255) / 256;
  int PB = (ET + PCHUNK - 1) / PCHUNK;
  int nbk = (N + 255) >> 8;

  char* p = (char*)d_ws;
  u16* x_b   = (u16*)p; p += (size_t)N * 128 * 2;
  u16* aggx  = (u16*)p; p += (size_t)N * 512 * 2;
  u16* raw1  = (u16*)p; p += (size_t)N * 512 * 2;
  u16* h1_b  = (u16*)p; p += (size_t)N * 512 * 2;
  u16* raw2b = (u16*)p; p += (size_t)N * 128 * 2;
  float* h2  = (float*)p; p += (size_t)N * 128 * 4;
  u16* W1t   = (u16*)p; p += 512 * 128 * 2;
  u16* W2t   = (u16*)p; p += 128 * 512 * 2;
  u16* wst   = (u16*)p; p += 16 * 128 * 2;
  float* sa1 = (float*)p; p += (size_t)N * 4 * 4;
  float* da1 = (float*)p; p += (size_t)N * 4 * 4;
  float* sa2 = (float*)p; p += (size_t)N * 4;
  float* da2 = (float*)p; p += (size_t)N * 4;
  int* counts = (int*)p; p += (size_t)N * 4;
  int* indptr = (int*)p; p += (size_t)(N + 1) * 4;
  int* bsum   = (int*)p; p += (size_t)nb * 4;
  int* boff   = (int*)p; p += (size_t)nb * 4;
  int* blockhist = (int*)p; p += (size_t)PB * 256 * 4;
  int* gbase  = (int*)p; p += (size_t)PB * 256 * 4;
  int* srcs   = (int*)p; p += (size_t)ET * 4;
  uint2* bpairs = (uint2*)p; p += (size_t)ET * 8;

  hipMemsetAsync(counts, 0, (size_t)N * sizeof(int), stream);

  // weight prep
  k_wprep<<<513, 256, 0, stream>>>(W1, W2, as1w, ad1w, W1t, W2t, wst);

  // edge counting + bucket histogram + x->bf16
  int cb = (N * 32 + 255) / 256;
  k_count_prep<<<PB + cb, 256, 0, stream>>>(ei, counts, blockhist, E, N, PB,
                                            x, (uint2*)x_b);

  // conv1 scores via MFMA
  k_score<<<(N + 255) / 256, 256, 0, stream>>>(x_b, wst, sa1, da1, N);

  // CSR indptr
  k_scanA<<<nb, 256, 0, stream>>>(counts, bsum, N);
  k_scanB<<<1, 1024, 0, stream>>>(bsum, boff, nb);
  k_scanC<<<nb, 256, 0, stream>>>(counts, boff, indptr, N);

  // contention-free bucket partition then per-bucket scatter
  k_colscan<<<1, 256, 0, stream>>>(blockhist, indptr, gbase, N, PB);
  k_place<<<PB, 256, 0, stream>>>(ei, gbase, bpairs, E, N);
  k_scatter2<<<nbk, 256, 0, stream>>>(bpairs, indptr, srcs, N);

  // conv1
  k_aggx<<<(N + 7) / 8, 256, 0, stream>>>((const u32*)x_b, indptr, srcs,
                                          (const float4*)sa1, (const float4*)da1,
                                          (u32*)aggx, N);
  dim3 gridh((N + 127) / 128, 4);
  k_gemm_head<<<gridh, 256, 0, stream>>>(aggx, W1t, b1, raw1, N);
  k_ln512<<<(N + 3) / 4, 256, 0, stream>>>(raw1, g1, be1, h1_b, N);

  // conv2: GEMM with fused attention-score epilogue
  k_gemm2_att<<<(N + 127) / 128, 256, 0, stream>>>(h1_b, W2t, as2w, ad2w,
                                                   raw2b, sa2, da2, N);
  k_agg2f<<<(N + 7) / 8, 256, 0, stream>>>((const u32*)raw2b, indptr, srcs, sa2, da2,
                                           b2, g2, be2, h2, N);

  // head
  k_head<<<GRAPHS, 256, 0, stream>>>(h2, batch, N, rW1, rb1, rg, rbe, rW2, rb2,
                                     (float*)d_out);
}